// Round 1
// baseline (1469.812 us; speedup 1.0000x reference)
//
#include <hip/hip_runtime.h>

#define N_NODES 20000
#define F_DIM 128
#define D_DIM 64
#define B_GR 8
#define E_EDGES 320000
#define A_ACT 512
#define NI_L 16
#define NCLS 16
#define EPW 8   // edges per wave in spmm

// ---------------- input_message = nf @ w_n2l + bias ----------------
__global__ __launch_bounds__(256) void k_n2l(const float* __restrict__ nf,
        const float* __restrict__ w, const float* __restrict__ bias,
        float* __restrict__ im) {
    __shared__ float Wl[F_DIM * D_DIM];             // 32 KB
    for (int i = threadIdx.x; i < F_DIM * D_DIM; i += 256) Wl[i] = w[i];
    __syncthreads();
    int lane = threadIdx.x & 63;
    int wid = (blockIdx.x * 256 + threadIdx.x) >> 6;
    int nw  = (gridDim.x * 256) >> 6;
    float b = bias[lane];
    for (int n = wid; n < N_NODES; n += nw) {
        const float* nfr = nf + (size_t)n * F_DIM;
        float acc = b;
        #pragma unroll 8
        for (int k = 0; k < F_DIM; ++k)
            acc = fmaf(nfr[k], Wl[k * D_DIM + lane], acc);
        im[(size_t)n * D_DIM + lane] = acc;
    }
}

// ---------------- spmm: pool[r] += ew * src[c]  (one wave = EPW edges) -----
template <bool RELU_SRC>
__global__ __launch_bounds__(256) void k_spmm(const float* __restrict__ src,
        size_t src_stride,
        const float* __restrict__ ew, const int* __restrict__ rows,
        const int* __restrict__ cols, float* __restrict__ pool) {
    int g    = blockIdx.y;
    int lane = threadIdx.x & 63;
    int wid  = blockIdx.x * 4 + (threadIdx.x >> 6);
    int e0   = wid * EPW;
    if (e0 >= E_EDGES) return;
    int e1 = min(e0 + EPW, E_EDGES);
    const float* s   = src + (size_t)g * src_stride;
    const float* ewg = ew  + (size_t)g * E_EDGES;
    const int*   rg  = rows + (size_t)g * E_EDGES;
    const int*   cg  = cols + (size_t)g * E_EDGES;
    float* pg = pool + (size_t)g * N_NODES * D_DIM;
    for (int e = e0; e < e1; ++e) {
        int   r = rg[e];
        int   c = cg[e];
        float w = ewg[e];
        float v = s[(size_t)c * D_DIM + lane];
        if (RELU_SRC) v = fmaxf(v, 0.f);
        atomicAdd(&pg[(size_t)r * D_DIM + lane], v * w);
    }
}

// ------- h = relu(pool @ conv_w + conv_b + im); optional graph-mean sum ----
__global__ __launch_bounds__(256) void k_gemm(const float* __restrict__ pool,
        const float* __restrict__ im, const float* __restrict__ W,
        const float* __restrict__ bias, float* __restrict__ hout,
        float* __restrict__ ge, int ge_base) {
    __shared__ float Wl[D_DIM * D_DIM];             // 16 KB
    for (int i = threadIdx.x; i < D_DIM * D_DIM; i += 256) Wl[i] = W[i];
    __syncthreads();
    int lane = threadIdx.x & 63;
    int wv   = threadIdx.x >> 6;                    // wave in block 0..3
    const int BPG = gridDim.x;
    int rpb = (N_NODES + BPG - 1) / BPG;            // rows per block
    int rpw = (rpb + 3) / 4;                        // rows per wave
    int r0  = blockIdx.x * rpb + wv * rpw;
    int r1  = min(r0 + rpw, min((blockIdx.x + 1) * rpb, N_NODES));
    size_t goff = (size_t)blockIdx.y * N_NODES * D_DIM;
    float b = bias[lane];
    float gsum = 0.f;
    for (int n = r0; n < r1; ++n) {
        const float* pr = pool + goff + (size_t)n * D_DIM;
        float acc = b;
        #pragma unroll
        for (int k = 0; k < D_DIM; ++k)
            acc = fmaf(pr[k], Wl[k * D_DIM + lane], acc);
        acc += im[(size_t)n * D_DIM + lane];
        acc = fmaxf(acc, 0.f);
        hout[goff + (size_t)n * D_DIM + lane] = acc;
        gsum += acc;
    }
    if (ge != nullptr && r1 > r0)
        atomicAdd(&ge[(ge_base + blockIdx.y) * D_DIM + lane], gsum);
}

// ---------------- gather action embeddings ----------------
__global__ __launch_bounds__(256) void k_gather_act(const float* __restrict__ h,
        size_t h_stride, const int* __restrict__ actions, int gb,
        float* __restrict__ act_emb) {
    int g = blockIdx.y;
    int lane = threadIdx.x & 63;
    int a = blockIdx.x * 4 + (threadIdx.x >> 6);
    if (a >= A_ACT) return;
    int act = actions[(size_t)(gb + g) * A_ACT + a];
    float v = h[(size_t)g * h_stride + (size_t)act * D_DIM + lane];
    act_emb[((size_t)(gb + g) * A_ACT + a) * D_DIM + lane] = v;
}

// ------- label embed (per graph) + graph_embed mean finalize ----------
__global__ __launch_bounds__(512) void k_small(const int* __restrict__ labels,
        const float* __restrict__ le1w, const float* __restrict__ le1b,
        const float* __restrict__ le2w, const float* __restrict__ le2b,
        float* __restrict__ ge, float* __restrict__ le) {
    int b = threadIdx.x >> 6;
    int lane = threadIdx.x & 63;
    ge[b * D_DIM + lane] *= (1.f / (float)N_NODES);
    float x = le1b[lane];
    #pragma unroll
    for (int i = 0; i < NI_L; ++i) {
        int cls = labels[b * NI_L + i];
        x += le1w[(i * NCLS + cls) * D_DIM + lane];
    }
    x = fmaxf(x, 0.f);
    float acc = le2b[lane];
    for (int hh = 0; hh < D_DIM; ++hh)
        acc = fmaf(__shfl(x, hh), le2w[hh * D_DIM + lane], acc);
    le[b * D_DIM + lane] = fmaxf(acc, 0.f);
}

// ------- raw_pred[b,a] = linout(relu(lin1([ge,le,act]))) -------------
__global__ __launch_bounds__(256) void k_tail(const float* __restrict__ ge,
        const float* __restrict__ le, const float* __restrict__ act_emb,
        const float* __restrict__ lin1w, const float* __restrict__ lin1b,
        const float* __restrict__ loutw, const float* __restrict__ loutb,
        float* __restrict__ raw) {
    __shared__ float Wl[192 * 64];                  // 48 KB
    for (int i = threadIdx.x; i < 192 * 64; i += 256) Wl[i] = lin1w[i];
    __syncthreads();
    int lane = threadIdx.x & 63;
    int wv = blockIdx.x * 4 + (threadIdx.x >> 6);
    if (wv >= B_GR * A_ACT) return;
    int b = wv >> 9;
    float e2 = act_emb[(size_t)wv * D_DIM + lane];
    const float* geb = ge + b * D_DIM;
    const float* leb = le + b * D_DIM;
    float z = lin1b[lane];
    #pragma unroll 4
    for (int k = 0; k < 64; ++k) z = fmaf(geb[k], Wl[k * 64 + lane], z);
    #pragma unroll 4
    for (int k = 0; k < 64; ++k) z = fmaf(leb[k], Wl[(64 + k) * 64 + lane], z);
    #pragma unroll 4
    for (int k = 0; k < 64; ++k) z = fmaf(__shfl(e2, k), Wl[(128 + k) * 64 + lane], z);
    z = fmaxf(z, 0.f);
    float r = z * loutw[lane];
    #pragma unroll
    for (int off = 32; off; off >>= 1) r += __shfl_xor(r, off);
    if (lane == 0) raw[wv] = r + loutb[0];
}

// ---------------- preds[b] = max_a raw[b,a] ----------------
__global__ __launch_bounds__(512) void k_max(const float* __restrict__ raw,
        float* __restrict__ out) {
    int b = threadIdx.x >> 6, lane = threadIdx.x & 63;
    float m = -INFINITY;
    for (int a = lane; a < A_ACT; a += 64) m = fmaxf(m, raw[b * A_ACT + a]);
    #pragma unroll
    for (int off = 32; off; off >>= 1) m = fmaxf(m, __shfl_xor(m, off));
    if (lane == 0) out[b] = m;
}

extern "C" void kernel_launch(void* const* d_in, const int* in_sizes, int n_in,
                              void* d_out, int out_size, void* d_ws, size_t ws_size,
                              hipStream_t stream) {
    const float* nf      = (const float*)d_in[0];
    const float* w_n2l   = (const float*)d_in[1];
    const float* bias_n2l= (const float*)d_in[2];
    const float* conv_w  = (const float*)d_in[3];
    const float* conv_b  = (const float*)d_in[4];
    const float* lin1_w  = (const float*)d_in[5];
    const float* lin1_b  = (const float*)d_in[6];
    const float* linout_w= (const float*)d_in[7];
    const float* linout_b= (const float*)d_in[8];
    const float* le1_w   = (const float*)d_in[9];
    const float* le1_b   = (const float*)d_in[10];
    const float* le2_w   = (const float*)d_in[11];
    const float* le2_b   = (const float*)d_in[12];
    const float* edge_w  = (const float*)d_in[13];
    const int*   rows    = (const int*)d_in[14];
    const int*   cols    = (const int*)d_in[15];
    const int*   labels  = (const int*)d_in[16];
    const int*   actions = (const int*)d_in[17];
    float* out = (float*)d_out;

    const size_t NE = (size_t)N_NODES * D_DIM;      // 1.28 M floats
    const size_t ACT_SZ = (size_t)B_GR * A_ACT * D_DIM;
    const size_t SMALL  = 512 + 512 + (size_t)B_GR * A_ACT;

    size_t need_batched = NE + 8 * NE + 8 * NE + ACT_SZ + SMALL;
    bool batched = ws_size >= need_batched * sizeof(float);

    float* ws = (float*)d_ws;
    const int spmm_bpg = (E_EDGES + 4 * EPW - 1) / (4 * EPW);   // 10000

    if (batched) {
        float* im   = ws;
        float* h    = im + NE;
        float* pool = h + 8 * NE;
        float* act  = pool + 8 * NE;
        float* ge   = act + ACT_SZ;
        float* le   = ge + 512;
        float* raw  = le + 512;

        k_n2l<<<512, 256, 0, stream>>>(nf, w_n2l, bias_n2l, im);

        hipMemsetAsync(pool, 0, 8 * NE * sizeof(float), stream);
        hipMemsetAsync(ge, 0, 512 * sizeof(float), stream);

        dim3 gs(spmm_bpg, 8), gg(32, 8), ga(128, 8);
        // level 0: src = relu(im), shared across graphs
        k_spmm<true><<<gs, 256, 0, stream>>>(im, 0, edge_w, rows, cols, pool);
        k_gemm<<<gg, 256, 0, stream>>>(pool, im, conv_w, conv_b, h, nullptr, 0);
        // level 1
        hipMemsetAsync(pool, 0, 8 * NE * sizeof(float), stream);
        k_spmm<false><<<gs, 256, 0, stream>>>(h, NE, edge_w, rows, cols, pool);
        k_gemm<<<gg, 256, 0, stream>>>(pool, im, conv_w, conv_b, h, ge, 0);

        k_gather_act<<<ga, 256, 0, stream>>>(h, NE, actions, 0, act);
        k_small<<<1, 512, 0, stream>>>(labels, le1_w, le1_b, le2_w, le2_b, ge, le);
        k_tail<<<(B_GR * A_ACT) / 4, 256, 0, stream>>>(ge, le, act, lin1_w, lin1_b,
                                                       linout_w, linout_b, raw);
        k_max<<<1, 512, 0, stream>>>(raw, out);
    } else {
        // sequential per-graph fallback (~17 MB workspace)
        float* im   = ws;
        float* h    = im + NE;
        float* pool = h + NE;
        float* act  = pool + NE;
        float* ge   = act + ACT_SZ;
        float* le   = ge + 512;
        float* raw  = le + 512;

        k_n2l<<<512, 256, 0, stream>>>(nf, w_n2l, bias_n2l, im);
        hipMemsetAsync(ge, 0, 512 * sizeof(float), stream);

        dim3 gs(spmm_bpg, 1), gg(32, 1), ga(128, 1);
        for (int b = 0; b < B_GR; ++b) {
            const float* ewb = edge_w + (size_t)b * E_EDGES;
            const int*   rb  = rows + (size_t)b * E_EDGES;
            const int*   cb  = cols + (size_t)b * E_EDGES;
            hipMemsetAsync(pool, 0, NE * sizeof(float), stream);
            k_spmm<true><<<gs, 256, 0, stream>>>(im, 0, ewb, rb, cb, pool);
            k_gemm<<<gg, 256, 0, stream>>>(pool, im, conv_w, conv_b, h, nullptr, 0);
            hipMemsetAsync(pool, 0, NE * sizeof(float), stream);
            k_spmm<false><<<gs, 256, 0, stream>>>(h, 0, ewb, rb, cb, pool);
            k_gemm<<<gg, 256, 0, stream>>>(pool, im, conv_w, conv_b, h, ge, b);
            k_gather_act<<<ga, 256, 0, stream>>>(h, 0, actions, b, act);
        }
        k_small<<<1, 512, 0, stream>>>(labels, le1_w, le1_b, le2_w, le2_b, ge, le);
        k_tail<<<(B_GR * A_ACT) / 4, 256, 0, stream>>>(ge, le, act, lin1_w, lin1_b,
                                                       linout_w, linout_b, raw);
        k_max<<<1, 512, 0, stream>>>(raw, out);
    }
}

// Round 3
// 909.332 us; speedup vs baseline: 1.6164x; 1.6164x over previous
//
#include <hip/hip_runtime.h>

#define N_NODES 20000
#define F_DIM 128
#define D_DIM 64
#define B_GR 8
#define E_EDGES 320000
#define A_ACT 512
#define NI_L 16
#define NCLS 16

// ---------------- input_message = nf @ w_n2l + bias ----------------
__global__ __launch_bounds__(256) void k_n2l(const float* __restrict__ nf,
        const float* __restrict__ w, const float* __restrict__ bias,
        float* __restrict__ im) {
    __shared__ float Wl[F_DIM * D_DIM];             // 32 KB
    for (int i = threadIdx.x; i < F_DIM * D_DIM; i += 256) Wl[i] = w[i];
    __syncthreads();
    int lane = threadIdx.x & 63;
    int wid = (blockIdx.x * 256 + threadIdx.x) >> 6;
    int nw  = (gridDim.x * 256) >> 6;
    float b = bias[lane];
    for (int n = wid; n < N_NODES; n += nw) {
        const float* nfr = nf + (size_t)n * F_DIM;
        float acc = b;
        #pragma unroll 8
        for (int k = 0; k < F_DIM; ++k)
            acc = fmaf(nfr[k], Wl[k * D_DIM + lane], acc);
        im[(size_t)n * D_DIM + lane] = acc;
    }
}

// ---------------- CSR build: histogram ----------------
__global__ __launch_bounds__(256) void k_hist(const int* __restrict__ rows,
        int* __restrict__ cnt) {
    const int n = B_GR * E_EDGES;
    for (int i = blockIdx.x * 256 + threadIdx.x; i < n; i += gridDim.x * 256) {
        int g = i / E_EDGES;
        atomicAdd(&cnt[g * N_NODES + rows[i]], 1);
    }
}

// ---------------- CSR build: per-graph exclusive scan (1 block/graph) ------
__global__ __launch_bounds__(1024) void k_scan(const int* __restrict__ cnt,
        int* __restrict__ ptr, int* __restrict__ cur) {
    int g = blockIdx.x;
    __shared__ int part[1024];
    int t = threadIdx.x;
    int loc[20];
    int sum = 0;
    #pragma unroll
    for (int i = 0; i < 20; ++i) {
        int idx = t * 20 + i;
        loc[i] = sum;
        if (idx < N_NODES) sum += cnt[g * N_NODES + idx];
    }
    part[t] = sum;
    __syncthreads();
    for (int off = 1; off < 1024; off <<= 1) {
        int v = (t >= off) ? part[t - off] : 0;
        __syncthreads();
        part[t] += v;
        __syncthreads();
    }
    int excl = part[t] - sum;
    #pragma unroll
    for (int i = 0; i < 20; ++i) {
        int idx = t * 20 + i;
        if (idx < N_NODES) {
            int v = excl + loc[i];
            ptr[g * (N_NODES + 1) + idx] = v;
            cur[g * N_NODES + idx] = v;
        }
    }
    if (t == 0) ptr[g * (N_NODES + 1) + N_NODES] = part[1023];
}

// ---------------- CSR build: scatter (col, weight) into sorted slots -------
__global__ __launch_bounds__(256) void k_scatter(const int* __restrict__ rows,
        const int* __restrict__ cols, const float* __restrict__ ew,
        int* __restrict__ cur, float2* __restrict__ cw) {
    const int n = B_GR * E_EDGES;
    for (int i = blockIdx.x * 256 + threadIdx.x; i < n; i += gridDim.x * 256) {
        int g = i / E_EDGES;
        int pos = atomicAdd(&cur[g * N_NODES + rows[i]], 1);
        cw[(size_t)g * E_EDGES + pos] = make_float2(__int_as_float(cols[i]), ew[i]);
    }
}

// ---- fused level: hout[n] = relu( (Σ_e w·src[c]) @ conv_w + conv_b + im[n] )
// NGR graphs per launch; src and hout must NOT alias.
template <bool RELU_SRC, bool DO_GE, int NGR>
__global__ __launch_bounds__(256) void k_level(const float* __restrict__ src,
        size_t src_stride, const int* __restrict__ ptr,
        const float2* __restrict__ cw, const float* __restrict__ im,
        const float* __restrict__ convw, const float* __restrict__ convb,
        float* __restrict__ hout, size_t hout_stride,
        float* __restrict__ ge, int gbase) {
    int lane = threadIdx.x & 63;
    int wv   = threadIdx.x >> 6;
    int gl   = blockIdx.x & (NGR - 1);       // local graph (XCD-affine)
    int gg   = gbase + gl;                   // global graph
    int chunk = blockIdx.x / NGR;
    const int CH = gridDim.x / NGR;
    int waves_per_graph = CH * 4;
    int npw = (N_NODES + waves_per_graph - 1) / waves_per_graph;
    int n0 = (chunk * 4 + wv) * npw;
    int n1 = min(n0 + npw, N_NODES);

    float W[64];
    #pragma unroll
    for (int k = 0; k < 64; ++k) W[k] = convw[k * 64 + lane];
    float bc = convb[lane];

    const float*  sg  = src + (size_t)gl * src_stride;
    const int*    pg  = ptr + gg * (N_NODES + 1);
    const float2* cwg = cw + (size_t)gg * E_EDGES;
    float* hg = hout + (size_t)gl * hout_stride;
    float gsum = 0.f;

    for (int n = n0; n < n1; ++n) {
        int s0 = pg[n], s1 = pg[n + 1];
        float acc = 0.f;
        int e = s0;
        for (; e + 4 <= s1; e += 4) {                 // 4 independent gathers
            float2 c0 = cwg[e], c1 = cwg[e+1], c2 = cwg[e+2], c3 = cwg[e+3];
            float v0 = sg[(size_t)__float_as_int(c0.x) * D_DIM + lane];
            float v1 = sg[(size_t)__float_as_int(c1.x) * D_DIM + lane];
            float v2 = sg[(size_t)__float_as_int(c2.x) * D_DIM + lane];
            float v3 = sg[(size_t)__float_as_int(c3.x) * D_DIM + lane];
            if (RELU_SRC) {
                v0 = fmaxf(v0, 0.f); v1 = fmaxf(v1, 0.f);
                v2 = fmaxf(v2, 0.f); v3 = fmaxf(v3, 0.f);
            }
            acc = fmaf(v0, c0.y, acc);
            acc = fmaf(v1, c1.y, acc);
            acc = fmaf(v2, c2.y, acc);
            acc = fmaf(v3, c3.y, acc);
        }
        for (; e < s1; ++e) {
            float2 cv = cwg[e];
            float v = sg[(size_t)__float_as_int(cv.x) * D_DIM + lane];
            if (RELU_SRC) v = fmaxf(v, 0.f);
            acc = fmaf(v, cv.y, acc);
        }
        float hv = bc;
        #pragma unroll
        for (int k = 0; k < 64; ++k) {
            float pk = __int_as_float(
                __builtin_amdgcn_readlane(__float_as_int(acc), k));
            hv = fmaf(pk, W[k], hv);
        }
        hv += im[(size_t)n * D_DIM + lane];
        hv = fmaxf(hv, 0.f);
        hg[(size_t)n * D_DIM + lane] = hv;
        gsum += hv;
    }
    if (DO_GE && n1 > n0) atomicAdd(&ge[gg * D_DIM + lane], gsum);
}

// ---------------- gather action embeddings (chunk of NGR graphs) ----------
__global__ __launch_bounds__(256) void k_gather_act(const float* __restrict__ h,
        size_t h_stride, const int* __restrict__ actions, int gbase,
        float* __restrict__ act_emb) {
    int gl = blockIdx.y;
    int gg = gbase + gl;
    int lane = threadIdx.x & 63;
    int a = blockIdx.x * 4 + (threadIdx.x >> 6);
    if (a >= A_ACT) return;
    int act = actions[(size_t)gg * A_ACT + a];
    float v = h[(size_t)gl * h_stride + (size_t)act * D_DIM + lane];
    act_emb[((size_t)gg * A_ACT + a) * D_DIM + lane] = v;
}

// ------- label embed (per graph) + graph_embed mean finalize ----------
__global__ __launch_bounds__(512) void k_small(const int* __restrict__ labels,
        const float* __restrict__ le1w, const float* __restrict__ le1b,
        const float* __restrict__ le2w, const float* __restrict__ le2b,
        float* __restrict__ ge, float* __restrict__ le) {
    int b = threadIdx.x >> 6;
    int lane = threadIdx.x & 63;
    ge[b * D_DIM + lane] *= (1.f / (float)N_NODES);
    float x = le1b[lane];
    #pragma unroll
    for (int i = 0; i < NI_L; ++i) {
        int cls = labels[b * NI_L + i];
        x += le1w[(i * NCLS + cls) * D_DIM + lane];
    }
    x = fmaxf(x, 0.f);
    float acc = le2b[lane];
    for (int hh = 0; hh < D_DIM; ++hh)
        acc = fmaf(__shfl(x, hh), le2w[hh * D_DIM + lane], acc);
    le[b * D_DIM + lane] = fmaxf(acc, 0.f);
}

// ------- raw_pred[b,a] = linout(relu(lin1([ge,le,act]))) -------------
__global__ __launch_bounds__(256) void k_tail(const float* __restrict__ ge,
        const float* __restrict__ le, const float* __restrict__ act_emb,
        const float* __restrict__ lin1w, const float* __restrict__ lin1b,
        const float* __restrict__ loutw, const float* __restrict__ loutb,
        float* __restrict__ raw) {
    __shared__ float Wl[192 * 64];                  // 48 KB
    for (int i = threadIdx.x; i < 192 * 64; i += 256) Wl[i] = lin1w[i];
    __syncthreads();
    int lane = threadIdx.x & 63;
    int wv = blockIdx.x * 4 + (threadIdx.x >> 6);
    if (wv >= B_GR * A_ACT) return;
    int b = wv >> 9;
    float e2 = act_emb[(size_t)wv * D_DIM + lane];
    const float* geb = ge + b * D_DIM;
    const float* leb = le + b * D_DIM;
    float z = lin1b[lane];
    #pragma unroll 4
    for (int k = 0; k < 64; ++k) z = fmaf(geb[k], Wl[k * 64 + lane], z);
    #pragma unroll 4
    for (int k = 0; k < 64; ++k) z = fmaf(leb[k], Wl[(64 + k) * 64 + lane], z);
    #pragma unroll 4
    for (int k = 0; k < 64; ++k) z = fmaf(__shfl(e2, k), Wl[(128 + k) * 64 + lane], z);
    z = fmaxf(z, 0.f);
    float r = z * loutw[lane];
    #pragma unroll
    for (int off = 32; off; off >>= 1) r += __shfl_xor(r, off);
    if (lane == 0) raw[wv] = r + loutb[0];
}

// ---------------- preds[b] = max_a raw[b,a] ----------------
__global__ __launch_bounds__(512) void k_max(const float* __restrict__ raw,
        float* __restrict__ out) {
    int b = threadIdx.x >> 6, lane = threadIdx.x & 63;
    float m = -INFINITY;
    for (int a = lane; a < A_ACT; a += 64) m = fmaxf(m, raw[b * A_ACT + a]);
    #pragma unroll
    for (int off = 32; off; off >>= 1) m = fmaxf(m, __shfl_xor(m, off));
    if (lane == 0) out[b] = m;
}

extern "C" void kernel_launch(void* const* d_in, const int* in_sizes, int n_in,
                              void* d_out, int out_size, void* d_ws, size_t ws_size,
                              hipStream_t stream) {
    const float* nf      = (const float*)d_in[0];
    const float* w_n2l   = (const float*)d_in[1];
    const float* bias_n2l= (const float*)d_in[2];
    const float* conv_w  = (const float*)d_in[3];
    const float* conv_b  = (const float*)d_in[4];
    const float* lin1_w  = (const float*)d_in[5];
    const float* lin1_b  = (const float*)d_in[6];
    const float* linout_w= (const float*)d_in[7];
    const float* linout_b= (const float*)d_in[8];
    const float* le1_w   = (const float*)d_in[9];
    const float* le1_b   = (const float*)d_in[10];
    const float* le2_w   = (const float*)d_in[11];
    const float* le2_b   = (const float*)d_in[12];
    const float* edge_w  = (const float*)d_in[13];
    const int*   rows    = (const int*)d_in[14];
    const int*   cols    = (const int*)d_in[15];
    const int*   labels  = (const int*)d_in[16];
    const int*   actions = (const int*)d_in[17];
    float* out = (float*)d_out;

    const size_t NE = (size_t)N_NODES * D_DIM;      // 1.28 M floats

    // ---- workspace carve (~79.8 MB; R1 proved ws_size >= 88.1 MB) ----
    float2* cw  = (float2*)d_ws;                    // 2,560,000 float2, 8B-aligned
    float* im   = (float*)(cw + (size_t)B_GR * E_EDGES);
    float* h    = im + NE;                          // 8*NE  (level-0 out)
    float* hA   = h + 8 * NE;                       // 2*NE  (level-1 chunk out)
    float* act  = hA + 2 * NE;
    float* ge   = act + (size_t)B_GR * A_ACT * D_DIM;
    float* le   = ge + 512;
    float* raw  = le + 512;
    int*   cnt  = (int*)(raw + B_GR * A_ACT);
    int*   ptr  = cnt + B_GR * N_NODES;
    int*   cur  = ptr + B_GR * (N_NODES + 1);

    // ---- independent prologue ----
    k_n2l<<<512, 256, 0, stream>>>(nf, w_n2l, bias_n2l, im);
    hipMemsetAsync(cnt, 0, (size_t)B_GR * N_NODES * sizeof(int), stream);
    hipMemsetAsync(ge, 0, 512 * sizeof(float), stream);

    // ---- CSR build (rows/cols shared by both levels) ----
    k_hist<<<2048, 256, 0, stream>>>(rows, cnt);
    k_scan<<<B_GR, 1024, 0, stream>>>(cnt, ptr, cur);
    k_scatter<<<2048, 256, 0, stream>>>(rows, cols, edge_w, cur, cw);

    // ---- level 0: all 8 graphs, src=im (shared), out=h. No aliasing. ----
    k_level<true, false, 8><<<128 * 8, 256, 0, stream>>>(
            im, 0, ptr, cw, im, conv_w, conv_b, h, NE, nullptr, 0);

    // ---- level 1 in 4 chunks of 2 graphs: src=h[g], out=hA (no alias) ----
    for (int c = 0; c < 4; ++c) {
        int gbase = 2 * c;
        k_level<false, true, 2><<<256 * 2, 256, 0, stream>>>(
                h + (size_t)gbase * NE, NE, ptr, cw, im, conv_w, conv_b,
                hA, NE, ge, gbase);
        dim3 ga(128, 2);
        k_gather_act<<<ga, 256, 0, stream>>>(hA, NE, actions, gbase, act);
    }

    // ---- tail ----
    k_small<<<1, 512, 0, stream>>>(labels, le1_w, le1_b, le2_w, le2_b, ge, le);
    k_tail<<<(B_GR * A_ACT) / 4, 256, 0, stream>>>(ge, le, act, lin1_w, lin1_b,
                                                   linout_w, linout_b, raw);
    k_max<<<1, 512, 0, stream>>>(raw, out);
}

// Round 4
// 686.891 us; speedup vs baseline: 2.1398x; 1.3238x over previous
//
#include <hip/hip_runtime.h>

#define N_NODES 20000
#define F_DIM 128
#define D_DIM 64
#define B_GR 8
#define E_EDGES 320000
#define A_ACT 512
#define NI_L 16
#define NCLS 16

// ---------------- input_message = nf @ w_n2l + bias ----------------
__global__ __launch_bounds__(256) void k_n2l(const float* __restrict__ nf,
        const float* __restrict__ w, const float* __restrict__ bias,
        float* __restrict__ im) {
    __shared__ float Wl[F_DIM * D_DIM];             // 32 KB
    for (int i = threadIdx.x; i < F_DIM * D_DIM; i += 256) Wl[i] = w[i];
    __syncthreads();
    int lane = threadIdx.x & 63;
    int wid = (blockIdx.x * 256 + threadIdx.x) >> 6;
    int nw  = (gridDim.x * 256) >> 6;
    float b = bias[lane];
    for (int n = wid; n < N_NODES; n += nw) {
        const float* nfr = nf + (size_t)n * F_DIM;
        float acc = b;
        #pragma unroll 8
        for (int k = 0; k < F_DIM; ++k)
            acc = fmaf(nfr[k], Wl[k * D_DIM + lane], acc);
        im[(size_t)n * D_DIM + lane] = acc;
    }
}

// ---------------- CSR build: histogram (XCD-affine: graph = block & 7) -----
__global__ __launch_bounds__(256) void k_hist(const int* __restrict__ rows,
        int* __restrict__ cnt) {
    int g = blockIdx.x & 7;
    int chunk = blockIdx.x >> 3;
    int nb = gridDim.x >> 3;
    int per = (E_EDGES + nb - 1) / nb;
    int e0 = chunk * per, e1 = min(e0 + per, E_EDGES);
    const int* rg = rows + (size_t)g * E_EDGES;
    int* cg = cnt + g * N_NODES;
    for (int e = e0 + threadIdx.x; e < e1; e += 256)
        atomicAdd(&cg[rg[e]], 1);
}

// ---------------- CSR build: per-graph exclusive scan (1 block/graph) ------
__global__ __launch_bounds__(1024) void k_scan(const int* __restrict__ cnt,
        int* __restrict__ ptr, int* __restrict__ cur) {
    int g = blockIdx.x;
    __shared__ int part[1024];
    int t = threadIdx.x;
    int loc[20];
    int sum = 0;
    #pragma unroll
    for (int i = 0; i < 20; ++i) {
        int idx = t * 20 + i;
        loc[i] = sum;
        if (idx < N_NODES) sum += cnt[g * N_NODES + idx];
    }
    part[t] = sum;
    __syncthreads();
    for (int off = 1; off < 1024; off <<= 1) {
        int v = (t >= off) ? part[t - off] : 0;
        __syncthreads();
        part[t] += v;
        __syncthreads();
    }
    int excl = part[t] - sum;
    #pragma unroll
    for (int i = 0; i < 20; ++i) {
        int idx = t * 20 + i;
        if (idx < N_NODES) {
            int v = excl + loc[i];
            ptr[g * (N_NODES + 1) + idx] = v;
            cur[g * N_NODES + idx] = v;
        }
    }
    if (t == 0) ptr[g * (N_NODES + 1) + N_NODES] = part[1023];
}

// ------- CSR build: scatter (col,w) into sorted slots (XCD-affine) --------
__global__ __launch_bounds__(256) void k_scatter(const int* __restrict__ rows,
        const int* __restrict__ cols, const float* __restrict__ ew,
        int* __restrict__ cur, float2* __restrict__ cw) {
    int g = blockIdx.x & 7;
    int chunk = blockIdx.x >> 3;
    int nb = gridDim.x >> 3;
    int per = (E_EDGES + nb - 1) / nb;
    int e0 = chunk * per, e1 = min(e0 + per, E_EDGES);
    const int*   rg = rows + (size_t)g * E_EDGES;
    const int*   cg = cols + (size_t)g * E_EDGES;
    const float* wg = ew   + (size_t)g * E_EDGES;
    int* curg = cur + g * N_NODES;
    float2* cwg = cw + (size_t)g * E_EDGES;
    for (int e = e0 + threadIdx.x; e < e1; e += 256) {
        int pos = atomicAdd(&curg[rg[e]], 1);
        cwg[pos] = make_float2(__int_as_float(cg[e]), wg[e]);
    }
}

// ---- fused level: hv[n] = relu( (Σ_e w·src[c]) @ conv_w + conv_b + im[n] )
// 8 graphs/launch, XCD-affine (g = block & 7). src must NOT alias hout.
template <bool RELU_SRC, bool DO_GE, bool STORE_H>
__global__ __launch_bounds__(256) void k_level(const float* __restrict__ src,
        size_t src_stride, const int* __restrict__ ptr,
        const float2* __restrict__ cw, const float* __restrict__ im,
        const float* __restrict__ convw, const float* __restrict__ convb,
        float* __restrict__ hout, float* __restrict__ ge) {
    int lane = threadIdx.x & 63;
    int wv   = threadIdx.x >> 6;
    int g    = blockIdx.x & 7;
    int chunk = blockIdx.x >> 3;
    const int CH = gridDim.x >> 3;
    int waves_per_graph = CH * 4;
    int npw = (N_NODES + waves_per_graph - 1) / waves_per_graph;
    int n0 = (chunk * 4 + wv) * npw;
    int n1 = min(n0 + npw, N_NODES);

    float W[64];
    #pragma unroll
    for (int k = 0; k < 64; ++k) W[k] = convw[k * 64 + lane];
    float bc = convb[lane];

    const float*  sg  = src + (size_t)g * src_stride;
    const int*    pg  = ptr + g * (N_NODES + 1);
    const float2* cwg = cw + (size_t)g * E_EDGES;
    float* hg = hout + (size_t)g * N_NODES * D_DIM;
    float gsum = 0.f;

    for (int n = n0; n < n1; ++n) {
        int s0 = pg[n], s1 = pg[n + 1];
        float acc = 0.f;
        int e = s0;
        for (; e + 4 <= s1; e += 4) {                 // 4 independent gathers
            float2 c0 = cwg[e], c1 = cwg[e+1], c2 = cwg[e+2], c3 = cwg[e+3];
            float v0 = sg[(size_t)__float_as_int(c0.x) * D_DIM + lane];
            float v1 = sg[(size_t)__float_as_int(c1.x) * D_DIM + lane];
            float v2 = sg[(size_t)__float_as_int(c2.x) * D_DIM + lane];
            float v3 = sg[(size_t)__float_as_int(c3.x) * D_DIM + lane];
            if (RELU_SRC) {
                v0 = fmaxf(v0, 0.f); v1 = fmaxf(v1, 0.f);
                v2 = fmaxf(v2, 0.f); v3 = fmaxf(v3, 0.f);
            }
            acc = fmaf(v0, c0.y, acc);
            acc = fmaf(v1, c1.y, acc);
            acc = fmaf(v2, c2.y, acc);
            acc = fmaf(v3, c3.y, acc);
        }
        for (; e < s1; ++e) {
            float2 cv = cwg[e];
            float v = sg[(size_t)__float_as_int(cv.x) * D_DIM + lane];
            if (RELU_SRC) v = fmaxf(v, 0.f);
            acc = fmaf(v, cv.y, acc);
        }
        float hv = bc;
        #pragma unroll
        for (int k = 0; k < 64; ++k) {
            float pk = __int_as_float(
                __builtin_amdgcn_readlane(__float_as_int(acc), k));
            hv = fmaf(pk, W[k], hv);
        }
        hv += im[(size_t)n * D_DIM + lane];
        hv = fmaxf(hv, 0.f);
        if (STORE_H) hg[(size_t)n * D_DIM + lane] = hv;
        gsum += hv;
    }
    if (DO_GE && n1 > n0) atomicAdd(&ge[g * D_DIM + lane], gsum);
}

// ---- recompute level-1 h at the 512 action nodes per graph (1 wave/action)
__global__ __launch_bounds__(256) void k_act(const float* __restrict__ h,
        const int* __restrict__ ptr, const float2* __restrict__ cw,
        const float* __restrict__ im, const float* __restrict__ convw,
        const float* __restrict__ convb, const int* __restrict__ actions,
        float* __restrict__ act_emb) {
    int lane = threadIdx.x & 63;
    int wv   = threadIdx.x >> 6;
    int g    = blockIdx.y;
    int a    = blockIdx.x * 4 + wv;
    int node = actions[(size_t)g * A_ACT + a];

    float W[64];
    #pragma unroll
    for (int k = 0; k < 64; ++k) W[k] = convw[k * 64 + lane];

    const float*  sg  = h + (size_t)g * N_NODES * D_DIM;
    const int*    pg  = ptr + g * (N_NODES + 1);
    const float2* cwg = cw + (size_t)g * E_EDGES;
    int s0 = pg[node], s1 = pg[node + 1];
    float acc = 0.f;
    int e = s0;
    for (; e + 4 <= s1; e += 4) {
        float2 c0 = cwg[e], c1 = cwg[e+1], c2 = cwg[e+2], c3 = cwg[e+3];
        float v0 = sg[(size_t)__float_as_int(c0.x) * D_DIM + lane];
        float v1 = sg[(size_t)__float_as_int(c1.x) * D_DIM + lane];
        float v2 = sg[(size_t)__float_as_int(c2.x) * D_DIM + lane];
        float v3 = sg[(size_t)__float_as_int(c3.x) * D_DIM + lane];
        acc = fmaf(v0, c0.y, acc);
        acc = fmaf(v1, c1.y, acc);
        acc = fmaf(v2, c2.y, acc);
        acc = fmaf(v3, c3.y, acc);
    }
    for (; e < s1; ++e) {
        float2 cv = cwg[e];
        float v = sg[(size_t)__float_as_int(cv.x) * D_DIM + lane];
        acc = fmaf(v, cv.y, acc);
    }
    float hv = convb[lane];
    #pragma unroll
    for (int k = 0; k < 64; ++k) {
        float pk = __int_as_float(
            __builtin_amdgcn_readlane(__float_as_int(acc), k));
        hv = fmaf(pk, W[k], hv);
    }
    hv += im[(size_t)node * D_DIM + lane];
    hv = fmaxf(hv, 0.f);
    act_emb[((size_t)g * A_ACT + a) * D_DIM + lane] = hv;
}

// ------- label embed (per graph) + graph_embed mean finalize ----------
__global__ __launch_bounds__(512) void k_small(const int* __restrict__ labels,
        const float* __restrict__ le1w, const float* __restrict__ le1b,
        const float* __restrict__ le2w, const float* __restrict__ le2b,
        float* __restrict__ ge, float* __restrict__ le) {
    int b = threadIdx.x >> 6;
    int lane = threadIdx.x & 63;
    ge[b * D_DIM + lane] *= (1.f / (float)N_NODES);
    float x = le1b[lane];
    #pragma unroll
    for (int i = 0; i < NI_L; ++i) {
        int cls = labels[b * NI_L + i];
        x += le1w[(i * NCLS + cls) * D_DIM + lane];
    }
    x = fmaxf(x, 0.f);
    float acc = le2b[lane];
    for (int hh = 0; hh < D_DIM; ++hh)
        acc = fmaf(__shfl(x, hh), le2w[hh * D_DIM + lane], acc);
    le[b * D_DIM + lane] = fmaxf(acc, 0.f);
}

// ------- raw_pred[b,a] = linout(relu(lin1([ge,le,act]))) -------------
__global__ __launch_bounds__(256) void k_tail(const float* __restrict__ ge,
        const float* __restrict__ le, const float* __restrict__ act_emb,
        const float* __restrict__ lin1w, const float* __restrict__ lin1b,
        const float* __restrict__ loutw, const float* __restrict__ loutb,
        float* __restrict__ raw) {
    __shared__ float Wl[192 * 64];                  // 48 KB
    for (int i = threadIdx.x; i < 192 * 64; i += 256) Wl[i] = lin1w[i];
    __syncthreads();
    int lane = threadIdx.x & 63;
    int wv = blockIdx.x * 4 + (threadIdx.x >> 6);
    if (wv >= B_GR * A_ACT) return;
    int b = wv >> 9;
    float e2 = act_emb[(size_t)wv * D_DIM + lane];
    const float* geb = ge + b * D_DIM;
    const float* leb = le + b * D_DIM;
    float z = lin1b[lane];
    #pragma unroll 4
    for (int k = 0; k < 64; ++k) z = fmaf(geb[k], Wl[k * 64 + lane], z);
    #pragma unroll 4
    for (int k = 0; k < 64; ++k) z = fmaf(leb[k], Wl[(64 + k) * 64 + lane], z);
    #pragma unroll 4
    for (int k = 0; k < 64; ++k) z = fmaf(__shfl(e2, k), Wl[(128 + k) * 64 + lane], z);
    z = fmaxf(z, 0.f);
    float r = z * loutw[lane];
    #pragma unroll
    for (int off = 32; off; off >>= 1) r += __shfl_xor(r, off);
    if (lane == 0) raw[wv] = r + loutb[0];
}

// ---------------- preds[b] = max_a raw[b,a] ----------------
__global__ __launch_bounds__(512) void k_max(const float* __restrict__ raw,
        float* __restrict__ out) {
    int b = threadIdx.x >> 6, lane = threadIdx.x & 63;
    float m = -INFINITY;
    for (int a = lane; a < A_ACT; a += 64) m = fmaxf(m, raw[b * A_ACT + a]);
    #pragma unroll
    for (int off = 32; off; off >>= 1) m = fmaxf(m, __shfl_xor(m, off));
    if (lane == 0) out[b] = m;
}

extern "C" void kernel_launch(void* const* d_in, const int* in_sizes, int n_in,
                              void* d_out, int out_size, void* d_ws, size_t ws_size,
                              hipStream_t stream) {
    const float* nf      = (const float*)d_in[0];
    const float* w_n2l   = (const float*)d_in[1];
    const float* bias_n2l= (const float*)d_in[2];
    const float* conv_w  = (const float*)d_in[3];
    const float* conv_b  = (const float*)d_in[4];
    const float* lin1_w  = (const float*)d_in[5];
    const float* lin1_b  = (const float*)d_in[6];
    const float* linout_w= (const float*)d_in[7];
    const float* linout_b= (const float*)d_in[8];
    const float* le1_w   = (const float*)d_in[9];
    const float* le1_b   = (const float*)d_in[10];
    const float* le2_w   = (const float*)d_in[11];
    const float* le2_b   = (const float*)d_in[12];
    const float* edge_w  = (const float*)d_in[13];
    const int*   rows    = (const int*)d_in[14];
    const int*   cols    = (const int*)d_in[15];
    const int*   labels  = (const int*)d_in[16];
    const int*   actions = (const int*)d_in[17];
    float* out = (float*)d_out;

    const size_t NE = (size_t)N_NODES * D_DIM;      // 1.28 M floats

    // ---- workspace carve (~70 MB; <= 79.8 MB proven safe in R3) ----
    float2* cw  = (float2*)d_ws;                    // B*E float2 (20.5 MB)
    float* im   = (float*)(cw + (size_t)B_GR * E_EDGES);   // NE
    float* h    = im + NE;                          // 8*NE (level-0 out)
    float* act  = h + 8 * NE;                       // B*A*D
    float* ge   = act + (size_t)B_GR * A_ACT * D_DIM;
    float* le   = ge + 512;
    float* raw  = le + 512;
    int*   cnt  = (int*)(raw + B_GR * A_ACT);
    int*   ptr  = cnt + B_GR * N_NODES;
    int*   cur  = ptr + B_GR * (N_NODES + 1);

    // ---- independent prologue ----
    k_n2l<<<512, 256, 0, stream>>>(nf, w_n2l, bias_n2l, im);
    hipMemsetAsync(cnt, 0, (size_t)B_GR * N_NODES * sizeof(int), stream);
    hipMemsetAsync(ge, 0, 512 * sizeof(float), stream);

    // ---- CSR build (XCD-affine; rows/cols shared by both levels) ----
    k_hist<<<2048, 256, 0, stream>>>(rows, cnt);
    k_scan<<<B_GR, 1024, 0, stream>>>(cnt, ptr, cur);
    k_scatter<<<2048, 256, 0, stream>>>(rows, cols, edge_w, cur, cw);

    // ---- level 0: src=im (shared), out=h ----
    k_level<true, false, true><<<128 * 8, 256, 0, stream>>>(
            im, 0, ptr, cw, im, conv_w, conv_b, h, nullptr);

    // ---- level 1: src=h, stores nothing, accumulates ge only ----
    k_level<false, true, false><<<128 * 8, 256, 0, stream>>>(
            h, NE, ptr, cw, im, conv_w, conv_b, h /*unused*/, ge);

    // ---- recompute level-1 h at action nodes ----
    dim3 ga(A_ACT / 4, B_GR);
    k_act<<<ga, 256, 0, stream>>>(h, ptr, cw, im, conv_w, conv_b, actions, act);

    // ---- tail ----
    k_small<<<1, 512, 0, stream>>>(labels, le1_w, le1_b, le2_w, le2_b, ge, le);
    k_tail<<<(B_GR * A_ACT) / 4, 256, 0, stream>>>(ge, le, act, lin1_w, lin1_b,
                                                   linout_w, linout_b, raw);
    k_max<<<1, 512, 0, stream>>>(raw, out);
}